// Round 2
// baseline (1017.675 us; speedup 1.0000x reference)
//
#include <hip/hip_runtime.h>
#include <stdint.h>

constexpr int D_MODEL = 4096;
constexpr int RANK = 32;
constexpr int TPB = 16;          // tokens per block
constexpr float SCALING = 0.5f;  // ALPHA / RANK = 16/32

__global__ __launch_bounds__(256, 4)
void lora_embed_kernel(const int* __restrict__ ids,
                       const int* __restrict__ wq,     // int8 values promoted to int32 by harness
                       const float* __restrict__ scale,
                       const float* __restrict__ A,
                       const float* __restrict__ Bm,
                       float* __restrict__ out)
{
    // A-fragments staged [r][t] so the 16 per-token a-values for a given r are
    // contiguous -> 4x ds_read_b128 broadcast reads per r instead of 16x b32.
    __shared__ float sA[RANK][TPB];
    __shared__ int sTok[TPB];

    const int tid = threadIdx.x;
    const int t0 = blockIdx.x * TPB;

    if (tid < TPB) sTok[tid] = ids[t0 + tid];
    __syncthreads();

    // Stage 16 adapter_A rows (x SCALING folded in): 512 floats, 2 per thread.
    {
        int i = tid;
        int t = i >> 5, r = i & 31;
        sA[r][t] = A[(int64_t)sTok[t] * RANK + r] * SCALING;
        i += 256;
        t = i >> 5; r = i & 31;
        sA[r][t] = A[(int64_t)sTok[t] * RANK + r] * SCALING;
    }
    __syncthreads();

    const float s = scale[0];

    int tok[TPB];
    #pragma unroll
    for (int t = 0; t < TPB; ++t) tok[t] = sTok[t];

    const float4* sA4 = (const float4*)&sA[0][0];  // [RANK][TPB/4]

    // 4 passes over D: each thread owns float4 at d = p*1024 + tid*4.
    for (int p = 0; p < 4; ++p) {
        const int d = p * 1024 + (tid << 2);

        float4 acc[TPB];
        #pragma unroll
        for (int t = 0; t < TPB; ++t) acc[t] = make_float4(0.f, 0.f, 0.f, 0.f);

        // B float4 loaded once per r, reused for all 16 tokens (16x L2-traffic cut).
        #pragma unroll 8
        for (int r = 0; r < RANK; ++r) {
            const float4 b = *(const float4*)(Bm + r * D_MODEL + d);
            float a[TPB];
            *(float4*)&a[0]  = sA4[r * 4 + 0];
            *(float4*)&a[4]  = sA4[r * 4 + 1];
            *(float4*)&a[8]  = sA4[r * 4 + 2];
            *(float4*)&a[12] = sA4[r * 4 + 3];
            #pragma unroll
            for (int t = 0; t < TPB; ++t) {
                acc[t].x += a[t] * b.x;
                acc[t].y += a[t] * b.y;
                acc[t].z += a[t] * b.z;
                acc[t].w += a[t] * b.w;
            }
        }

        // Epilogue: int32-promoted int8 dequant + add, coalesced 16B loads/stores.
        #pragma unroll
        for (int t = 0; t < TPB; ++t) {
            const int4 w = *(const int4*)(wq + (int64_t)tok[t] * D_MODEL + d);
            float4 o;
            o.x = (float)w.x * s + acc[t].x;
            o.y = (float)w.y * s + acc[t].y;
            o.z = (float)w.z * s + acc[t].z;
            o.w = (float)w.w * s + acc[t].w;
            *(float4*)(out + (int64_t)(t0 + t) * D_MODEL + d) = o;
        }
    }
}

extern "C" void kernel_launch(void* const* d_in, const int* in_sizes, int n_in,
                              void* d_out, int out_size, void* d_ws, size_t ws_size,
                              hipStream_t stream)
{
    const int*   ids   = (const int*)d_in[0];
    const int*   wq    = (const int*)d_in[1];   // int8 promoted to int32 by harness
    const float* scale = (const float*)d_in[2];
    const float* A     = (const float*)d_in[3];
    const float* Bm    = (const float*)d_in[4];
    float* out = (float*)d_out;

    const int n_tok  = in_sizes[0];      // 4*4096 = 16384
    const int blocks = n_tok / TPB;      // 1024
    lora_embed_kernel<<<blocks, 256, 0, stream>>>(ids, wq, scale, A, Bm, out);
}